// Round 8
// baseline (1188.690 us; speedup 1.0000x reference)
//
#include <hip/hip_runtime.h>
#include <hip/hip_bf16.h>

#define N_NODES 100000
#define N_EDGES 1600000
#define DIM_IN  256
#define DIM_H   128

#define NBKT 782   // ceil(N_NODES / 128) buckets of 128 nodes

typedef __attribute__((ext_vector_type(8))) short short8;
typedef __attribute__((ext_vector_type(4))) float f32x4;

// ------------------------------------------------- edge_index width detect
__global__ __launch_bounds__(1024) void k_detect(const int* __restrict__ e,
                                                 int* __restrict__ flag) {
  __shared__ int s;
  if (threadIdx.x == 0) s = 0;
  __syncthreads();
  atomicOr(&s, e[2 * threadIdx.x + 1]);
  __syncthreads();
  if (threadIdx.x == 0) *flag = (s == 0) ? 1 : 0;
}

__device__ __forceinline__ int get_src(const int* e, int is64, int i) {
  return is64 ? e[2 * i] : e[i];
}
__device__ __forceinline__ int get_dst(const int* e, int is64, int i) {
  return is64 ? e[2 * (N_EDGES + i)] : e[N_EDGES + i];
}

__global__ __launch_bounds__(256) void k_zero(int* __restrict__ p, int n) {
  int i = blockIdx.x * 256 + threadIdx.x;
  if (i < n) p[i] = 0;
}

// ---------------------------------------------------- bucketed CSR build
// A: per-bucket edge histogram (782 counters)
__global__ __launch_bounds__(256) void k_binc(const int* __restrict__ eidx,
                                              const int* __restrict__ flag,
                                              int* __restrict__ bcur) {
  int e = blockIdx.x * 256 + threadIdx.x;
  int is64 = *flag;
  if (e < N_EDGES) {
    unsigned s = (unsigned)get_src(eidx, is64, e);
    unsigned d = (unsigned)get_dst(eidx, is64, e);
    if (s < N_NODES && d < N_NODES) atomicAdd(&bcur[d >> 7], 1);
  }
}

// B: scan bucket counts -> bbase[0..NBKT] starts (+total), bcur = starts copy
__global__ __launch_bounds__(1024) void k_bscan(int* __restrict__ bcur,
                                                int* __restrict__ bbase) {
  __shared__ int sm[1024];
  int t = threadIdx.x;
  int v = (t < NBKT) ? bcur[t] : 0;
  sm[t] = v;
  __syncthreads();
  for (int d = 1; d < 1024; d <<= 1) {
    int u = (t >= d) ? sm[t - d] : 0;
    __syncthreads();
    sm[t] += u;
    __syncthreads();
  }
  if (t < NBKT) {
    int excl = sm[t] - v;
    bbase[t] = excl;
    bcur[t] = excl;
    if (t == NBKT - 1) bbase[NBKT] = sm[t];
  }
}

// C: scatter (src,dst) records into bucket regions (L2-local line fills)
__global__ __launch_bounds__(256) void k_bin(const int* __restrict__ eidx,
                                             const int* __restrict__ flag,
                                             int* __restrict__ bcur,
                                             uint2* __restrict__ ebuf) {
  int e = blockIdx.x * 256 + threadIdx.x;
  int is64 = *flag;
  if (e < N_EDGES) {
    unsigned s = (unsigned)get_src(eidx, is64, e);
    unsigned d = (unsigned)get_dst(eidx, is64, e);
    if (s < N_NODES && d < N_NODES) {
      int pos = atomicAdd(&bcur[d >> 7], 1);
      ebuf[pos] = make_uint2(s, d);
    }
  }
}

// D: per bucket -> local histogram, scan, write off (ends) + dinv + csr
__global__ __launch_bounds__(256) void k_csr(const int* __restrict__ bbase,
                                             const uint2* __restrict__ ebuf,
                                             int* __restrict__ off,
                                             float* __restrict__ dinv,
                                             int* __restrict__ csr) {
  __shared__ int hist[128];
  __shared__ int scn[128];
  __shared__ int cur[128];
  const int b = blockIdx.x, t = threadIdx.x;
  const int n0 = b << 7;
  const int start = bbase[b], end = bbase[b + 1];
  if (t < 128) hist[t] = 0;
  __syncthreads();
  for (int i = start + t; i < end; i += 256) {
    uint2 er = ebuf[i];
    atomicAdd(&hist[er.y - n0], 1);
  }
  __syncthreads();
  if (t < 128) scn[t] = hist[t];
  __syncthreads();
  for (int d = 1; d < 128; d <<= 1) {
    int u = (t < 128 && t >= d) ? scn[t - d] : 0;
    __syncthreads();
    if (t < 128) scn[t] += u;
    __syncthreads();
  }
  if (t < 128) {
    int node = n0 + t;
    if (node < N_NODES) {
      off[node] = start + scn[t];                    // ends
      dinv[node] = rsqrtf(1.0f + (float)hist[t]);
      cur[t] = start + scn[t] - hist[t];             // starts
    }
  }
  __syncthreads();
  for (int i = start + t; i < end; i += 256) {
    uint2 er = ebuf[i];
    int pos = atomicAdd(&cur[er.y - n0], 1);
    csr[pos] = (int)er.x;
  }
}

// ---------------------------------------------------------------- bf16 utils
__device__ __forceinline__ ushort f2bf(float f) {
  unsigned u = __float_as_uint(f);
  unsigned r = (u + 0x7fffu + ((u >> 16) & 1u)) >> 16;
  return (ushort)r;
}
__device__ __forceinline__ float bf2f(ushort h) {
  return __uint_as_float(((unsigned)h) << 16);
}
__device__ __forceinline__ float bflo(unsigned u) {
  return __uint_as_float(u << 16);
}
__device__ __forceinline__ float bfhi(unsigned u) {
  return __uint_as_float(u & 0xffff0000u);
}
__device__ __forceinline__ unsigned bfpack(float a, float b) {
  return (unsigned)f2bf(a) | ((unsigned)f2bf(b) << 16);
}

__device__ __forceinline__ void load8(const float* p, float* o) {
  float4 a = reinterpret_cast<const float4*>(p)[0];
  float4 b = reinterpret_cast<const float4*>(p)[1];
  o[0] = a.x; o[1] = a.y; o[2] = a.z; o[3] = a.w;
  o[4] = b.x; o[5] = b.y; o[6] = b.z; o[7] = b.w;
}

// Split weight W[K x 128] into MFMA B-fragment planes (hi, lo).
__global__ __launch_bounds__(256)
void k_bsplit(const float* __restrict__ W, const int CH, ushort* __restrict__ outHi) {
  int idx = blockIdx.x * 256 + threadIdx.x;
  if (idx >= CH * 512) return;
  int n  = idx & 15;
  int qq = (idx >> 4) & 3;
  int nt = (idx >> 6) & 7;
  int c  = idx >> 9;
  int col = nt * 16 + n;
  short8 h8, l8;
#pragma unroll
  for (int j = 0; j < 8; ++j) {
    float v = W[(size_t)(c * 32 + qq * 8 + j) * DIM_H + col];
    ushort hb = f2bf(v);
    ushort lb = f2bf(v - bf2f(hb));
    h8[j] = (short)hb;
    l8[j] = (short)lb;
  }
  ((short8*)outHi)[idx] = h8;
  ((short8*)outHi)[CH * 512 + idx] = l8;
}

// ------------------------------------- MFMA GEMM, fp32 A (split), bf16 out
template <int K>
__global__ __launch_bounds__(256)
void k_gemm_x(const float* __restrict__ A, const ushort* __restrict__ Bfrag,
              const float* __restrict__ bias, ushort* __restrict__ C) {
  constexpr int CH = K / 32;
  __shared__ __align__(16) ushort AhiS[256 * 8];
  __shared__ __align__(16) ushort AloS[256 * 8];
  const int tid = threadIdx.x;
  const int m0 = blockIdx.x * 64;
  const int wave = tid >> 6, lane = tid & 63;
  const int m_l = lane & 15, quad = lane >> 4;
  const int rs = tid >> 2, q = tid & 3;

  f32x4 acc[2][4];
#pragma unroll
  for (int i = 0; i < 2; ++i)
#pragma unroll
    for (int j = 0; j < 4; ++j) acc[i][j] = (f32x4){0.f, 0.f, 0.f, 0.f};

  const short8* Bhi8 = (const short8*)Bfrag;
  const short8* Blo8 = Bhi8 + CH * 512;
  short8* Ah8 = (short8*)AhiS;
  short8* Al8 = (short8*)AloS;

  for (int c = 0; c < CH; ++c) {
    float v[8];
    const int gm = m0 + rs;
    if (gm < N_NODES) {
      load8(&A[(size_t)gm * K + c * 32 + q * 8], v);
    } else {
#pragma unroll
      for (int j = 0; j < 8; ++j) v[j] = 0.f;
    }
    short8 h8, l8;
#pragma unroll
    for (int j = 0; j < 8; ++j) {
      ushort hb = f2bf(v[j]);
      ushort lb = f2bf(v[j] - bf2f(hb));
      h8[j] = (short)hb;
      l8[j] = (short)lb;
    }
    __syncthreads();
    const int ent = (rs >> 4) * 64 + q * 16 + (rs & 15);
    Ah8[ent] = h8;
    Al8[ent] = l8;
    __syncthreads();

    short8 ahi[4], alo[4];
#pragma unroll
    for (int mt = 0; mt < 4; ++mt) {
      ahi[mt] = Ah8[mt * 64 + quad * 16 + m_l];
      alo[mt] = Al8[mt * 64 + quad * 16 + m_l];
    }
#pragma unroll
    for (int ntl = 0; ntl < 2; ++ntl) {
      const int bent = ((c * 8 + wave * 2 + ntl) * 4 + quad) * 16 + m_l;
      short8 bhi = Bhi8[bent];
      short8 blo = Blo8[bent];
#pragma unroll
      for (int mt = 0; mt < 4; ++mt) {
        acc[ntl][mt] = __builtin_amdgcn_mfma_f32_16x16x32_bf16(ahi[mt], bhi, acc[ntl][mt], 0, 0, 0);
        acc[ntl][mt] = __builtin_amdgcn_mfma_f32_16x16x32_bf16(ahi[mt], blo, acc[ntl][mt], 0, 0, 0);
        acc[ntl][mt] = __builtin_amdgcn_mfma_f32_16x16x32_bf16(alo[mt], bhi, acc[ntl][mt], 0, 0, 0);
      }
    }
  }

#pragma unroll
  for (int ntl = 0; ntl < 2; ++ntl) {
    const int colg = (wave * 2 + ntl) * 16 + m_l;
    const float bv = bias[colg];
#pragma unroll
    for (int mt = 0; mt < 4; ++mt) {
#pragma unroll
      for (int r = 0; r < 4; ++r) {
        const int rowg = m0 + mt * 16 + quad * 4 + r;
        if (rowg < N_NODES) {
          float t = fmaxf(acc[ntl][mt][r] + bv, 0.f);  // relu
          C[(size_t)rowg * DIM_H + colg] = f2bf(t);
        }
      }
    }
  }
}

// ------------------------------------- MFMA GEMM, bf16 A, bf16 out, row scale
__global__ __launch_bounds__(256)
void k_gemm_h(const ushort* __restrict__ A, const ushort* __restrict__ Bfrag,
              const float* __restrict__ scale, ushort* __restrict__ C) {
  constexpr int K = DIM_H, CH = K / 32;
  __shared__ __align__(16) ushort AS[256 * 8];
  const int tid = threadIdx.x;
  const int m0 = blockIdx.x * 64;
  const int wave = tid >> 6, lane = tid & 63;
  const int m_l = lane & 15, quad = lane >> 4;
  const int rs = tid >> 2, q = tid & 3;

  f32x4 acc[2][4];
#pragma unroll
  for (int i = 0; i < 2; ++i)
#pragma unroll
    for (int j = 0; j < 4; ++j) acc[i][j] = (f32x4){0.f, 0.f, 0.f, 0.f};

  const short8* Bhi8 = (const short8*)Bfrag;
  const short8* Blo8 = Bhi8 + CH * 512;
  short8* A8 = (short8*)AS;

#pragma unroll
  for (int c = 0; c < CH; ++c) {
    short8 h8 = {0, 0, 0, 0, 0, 0, 0, 0};
    const int gm = m0 + rs;
    if (gm < N_NODES)
      h8 = *reinterpret_cast<const short8*>(&A[(size_t)gm * DIM_H + c * 32 + q * 8]);
    __syncthreads();
    A8[(rs >> 4) * 64 + q * 16 + (rs & 15)] = h8;
    __syncthreads();

    short8 a[4];
#pragma unroll
    for (int mt = 0; mt < 4; ++mt) a[mt] = A8[mt * 64 + quad * 16 + m_l];
#pragma unroll
    for (int ntl = 0; ntl < 2; ++ntl) {
      const int bent = ((c * 8 + wave * 2 + ntl) * 4 + quad) * 16 + m_l;
      short8 bhi = Bhi8[bent];
      short8 blo = Blo8[bent];
#pragma unroll
      for (int mt = 0; mt < 4; ++mt) {
        acc[ntl][mt] = __builtin_amdgcn_mfma_f32_16x16x32_bf16(a[mt], bhi, acc[ntl][mt], 0, 0, 0);
        acc[ntl][mt] = __builtin_amdgcn_mfma_f32_16x16x32_bf16(a[mt], blo, acc[ntl][mt], 0, 0, 0);
      }
    }
  }

#pragma unroll
  for (int ntl = 0; ntl < 2; ++ntl) {
    const int colg = (wave * 2 + ntl) * 16 + m_l;
#pragma unroll
    for (int mt = 0; mt < 4; ++mt) {
#pragma unroll
      for (int r = 0; r < 4; ++r) {
        const int rowg = m0 + mt * 16 + quad * 4 + r;
        if (rowg < N_NODES)
          C[(size_t)rowg * DIM_H + colg] = f2bf(acc[ntl][mt][r] * scale[rowg]);
      }
    }
  }
}

// ---------------------------------------------------------------- CSR gather
__global__ __launch_bounds__(256)
void k_aggr_csr(const int* __restrict__ off, const int* __restrict__ csr,
                const ushort* __restrict__ t, const float* __restrict__ dinv,
                const float* __restrict__ bias, ushort* __restrict__ h) {
  int node = blockIdx.x * 4 + (threadIdx.x >> 6);
  if (node >= N_NODES) return;
  int lane = threadIdx.x & 63;
  const unsigned* tu = (const unsigned*)t;
  int start = (node == 0) ? 0 : off[node - 1];
  int end = off[node];
  unsigned su = tu[(size_t)node * 64 + lane];
  float ax = bflo(su), ay = bfhi(su);
  int e = start;
  for (; e + 3 < end; e += 4) {
    int s0 = csr[e], s1 = csr[e + 1], s2 = csr[e + 2], s3 = csr[e + 3];
    unsigned u0 = tu[(size_t)s0 * 64 + lane];
    unsigned u1 = tu[(size_t)s1 * 64 + lane];
    unsigned u2 = tu[(size_t)s2 * 64 + lane];
    unsigned u3 = tu[(size_t)s3 * 64 + lane];
    ax += (bflo(u0) + bflo(u1)) + (bflo(u2) + bflo(u3));
    ay += (bfhi(u0) + bfhi(u1)) + (bfhi(u2) + bfhi(u3));
  }
  for (; e < end; ++e) {
    unsigned u0 = tu[(size_t)csr[e] * 64 + lane];
    ax += bflo(u0);
    ay += bfhi(u0);
  }
  float dn = dinv[node];
  float2 b = ((const float2*)bias)[lane];
  ((unsigned*)h)[(size_t)node * 64 + lane] = bfpack(b.x + dn * ax, b.y + dn * ay);
}

// ---------------------------------------------------------------- head
__global__ __launch_bounds__(256)
void k_head(const ushort* __restrict__ h, const float* __restrict__ Wh,
            const float* __restrict__ bh, float* __restrict__ out) {
  int node = blockIdx.x * 4 + (threadIdx.x >> 6);
  int lane = threadIdx.x & 63;
  if (node >= N_NODES) return;
  unsigned u = ((const unsigned*)h)[(size_t)node * 64 + lane];
  float f0 = bflo(u), f1 = bfhi(u);
  float s0 = f0 * Wh[4 * lane + 0] + f1 * Wh[4 * lane + 2];
  float s1 = f0 * Wh[4 * lane + 1] + f1 * Wh[4 * lane + 3];
#pragma unroll
  for (int off = 32; off > 0; off >>= 1) {
    s0 += __shfl_down(s0, off);
    s1 += __shfl_down(s1, off);
  }
  if (lane == 0) {
    reinterpret_cast<float2*>(out)[node] = make_float2(s0 + bh[0], s1 + bh[1]);
  }
}

// --------------------------------------------- fp32 fallback (small ws) ----
__global__ __launch_bounds__(256) void k_count(const int* __restrict__ eidx,
                                               const int* __restrict__ flag,
                                               int* __restrict__ off) {
  int e = blockIdx.x * 256 + threadIdx.x;
  int is64 = *flag;
  if (e < N_EDGES) {
    unsigned d = (unsigned)get_dst(eidx, is64, e);
    if (d < N_NODES) atomicAdd(&off[d], 1);
  }
}

__global__ __launch_bounds__(256) void k_dinv_old(const int* __restrict__ off,
                                                  float* __restrict__ dinv) {
  int i = blockIdx.x * 256 + threadIdx.x;
  if (i < N_NODES) dinv[i] = rsqrtf(1.0f + (float)off[i]);
}

template <int K>
__global__ __launch_bounds__(256)
void k_gemm(const float* __restrict__ A, const float* __restrict__ B,
            const float* __restrict__ bias, const float* __restrict__ scale,
            float* __restrict__ C, const int do_relu) {
  __shared__ float As[64][33];
  const int tid = threadIdx.x;
  const int tx = tid & 15;
  const int ty = tid >> 4;
  const int m0 = blockIdx.x * 64;

  float acc[4][8];
#pragma unroll
  for (int i = 0; i < 4; ++i)
#pragma unroll
    for (int j = 0; j < 8; ++j) acc[i][j] = 0.f;

  const int rs = tid >> 2;
  const int ks = (tid & 3) * 8;

  for (int k0 = 0; k0 < K; k0 += 32) {
    float av8[8];
    const int gm = m0 + rs;
    if (gm < N_NODES) {
      load8(&A[(size_t)gm * K + k0 + ks], av8);
    } else {
#pragma unroll
      for (int j = 0; j < 8; ++j) av8[j] = 0.f;
    }
    __syncthreads();
#pragma unroll
    for (int j = 0; j < 8; ++j) As[rs][ks + j] = av8[j];
    __syncthreads();

    const float* Bp = B + (size_t)k0 * DIM_H + tx * 8;
#pragma unroll 4
    for (int k = 0; k < 32; ++k) {
      float bv[8];
      load8(Bp + (size_t)k * DIM_H, bv);
      float av[4];
#pragma unroll
      for (int rr = 0; rr < 4; ++rr) av[rr] = As[ty * 4 + rr][k];
#pragma unroll
      for (int rr = 0; rr < 4; ++rr)
#pragma unroll
        for (int cc = 0; cc < 8; ++cc)
          acc[rr][cc] = fmaf(av[rr], bv[cc], acc[rr][cc]);
    }
  }

  float bs[8];
  if (bias) {
    load8(bias + tx * 8, bs);
  } else {
#pragma unroll
    for (int j = 0; j < 8; ++j) bs[j] = 0.f;
  }
#pragma unroll
  for (int rr = 0; rr < 4; ++rr) {
    const int gm = m0 + ty * 4 + rr;
    if (gm < N_NODES) {
      float sc = scale ? scale[gm] : 1.0f;
      float v[8];
#pragma unroll
      for (int cc = 0; cc < 8; ++cc) {
        float t = acc[rr][cc] + bs[cc];
        if (do_relu) t = fmaxf(t, 0.f);
        v[cc] = t * sc;
      }
      float* Cp = &C[(size_t)gm * DIM_H + tx * 8];
      reinterpret_cast<float4*>(Cp)[0] = make_float4(v[0], v[1], v[2], v[3]);
      reinterpret_cast<float4*>(Cp)[1] = make_float4(v[4], v[5], v[6], v[7]);
    }
  }
}

__global__ __launch_bounds__(256)
void k_aggr_init(const float* __restrict__ t, const float* __restrict__ dinv,
                 const float* __restrict__ bias, float* __restrict__ h) {
  int idx = blockIdx.x * 256 + threadIdx.x;
  if (idx < N_NODES * DIM_H) {
    int i = idx >> 7;
    int c = idx & 127;
    float d = dinv[i];
    h[idx] = bias[c] + t[idx] * d * d;
  }
}

__global__ __launch_bounds__(256)
void k_aggr_edges(const int* __restrict__ eidx, const int* __restrict__ flag,
                  const float* __restrict__ t, const float* __restrict__ dinv,
                  float* __restrict__ h) {
  int e = blockIdx.x * 2 + (threadIdx.x >> 7);
  int c = threadIdx.x & 127;
  int is64 = *flag;
  if (e < N_EDGES) {
    unsigned s = (unsigned)get_src(eidx, is64, e);
    unsigned d = (unsigned)get_dst(eidx, is64, e);
    if (s < N_NODES && d < N_NODES) {
      float nrm = dinv[s] * dinv[d];
      unsafeAtomicAdd(&h[(size_t)d * DIM_H + c], t[(size_t)s * DIM_H + c] * nrm);
    }
  }
}

__global__ __launch_bounds__(256)
void k_head_f32(const float* __restrict__ h, const float* __restrict__ Wh,
                const float* __restrict__ bh, float* __restrict__ out) {
  int node = blockIdx.x * 4 + (threadIdx.x >> 6);
  int lane = threadIdx.x & 63;
  if (node >= N_NODES) return;
  float h0 = h[(size_t)node * DIM_H + lane];
  float h1 = h[(size_t)node * DIM_H + 64 + lane];
  float s0 = h0 * Wh[lane * 2 + 0] + h1 * Wh[(lane + 64) * 2 + 0];
  float s1 = h0 * Wh[lane * 2 + 1] + h1 * Wh[(lane + 64) * 2 + 1];
#pragma unroll
  for (int off = 32; off > 0; off >>= 1) {
    s0 += __shfl_down(s0, off);
    s1 += __shfl_down(s1, off);
  }
  if (lane == 0) {
    reinterpret_cast<float2*>(out)[node] = make_float2(s0 + bh[0], s1 + bh[1]);
  }
}

// ---------------------------------------------------------------- launch
extern "C" void kernel_launch(void* const* d_in, const int* in_sizes, int n_in,
                              void* d_out, int out_size, void* d_ws, size_t ws_size,
                              hipStream_t stream) {
  (void)in_sizes; (void)n_in; (void)out_size;
  const int* eidx = (const int*)d_in[0];
  const float* x  = (const float*)d_in[1];
  const float* Wi = (const float*)d_in[2];
  const float* bi = (const float*)d_in[3];
  const float* W1 = (const float*)d_in[4];
  const float* b1 = (const float*)d_in[5];
  const float* W2 = (const float*)d_in[6];
  const float* b2 = (const float*)d_in[7];
  const float* Wh = (const float*)d_in[8];
  const float* bh = (const float*)d_in[9];
  float* out = (float*)d_out;

  const int gE  = (N_EDGES + 255) / 256;
  const int gM  = (N_NODES + 63) / 64;
  const int gW  = (N_NODES + 3) / 4;

  char* ws = (char*)d_ws;
  int* flag = (int*)ws;
  k_detect<<<1, 1024, 0, stream>>>(eidx, flag);

  // tier 1 layout (ends at 71,478,528 B):
  // flag@0 | bbase@4096 (NBKT+1) | bcur@8192 (NBKT) | bfWi@16384 (128K) |
  // bfW1@147456 (64K) | bfW2@212992 (64K) | off@278528 | dinv@678528 |
  // csr@1078528 (6.4M) | ebuf@7478528 (12.8M) | bufA@20278528 | bufB@45878528
  const size_t need1 = 71478528;

  if (ws_size >= need1) {
    int*    bbase = (int*)(ws + 4096);
    int*    bcur  = (int*)(ws + 8192);
    ushort* bfWi  = (ushort*)(ws + 16384);
    ushort* bfW1  = (ushort*)(ws + 147456);
    ushort* bfW2  = (ushort*)(ws + 212992);
    int*    off   = (int*)(ws + 278528);
    float*  dinv  = (float*)(ws + 678528);
    int*    csr   = (int*)(ws + 1078528);
    uint2*  ebuf  = (uint2*)(ws + 7478528);
    ushort* bufA  = (ushort*)(ws + 20278528);
    ushort* bufB  = (ushort*)(ws + 45878528);

    // bucketed CSR build
    k_zero<<<(NBKT + 255) / 256, 256, 0, stream>>>(bcur, NBKT);
    k_binc<<<gE, 256, 0, stream>>>(eidx, flag, bcur);
    k_bscan<<<1, 1024, 0, stream>>>(bcur, bbase);
    k_bin<<<gE, 256, 0, stream>>>(eidx, flag, bcur, ebuf);
    k_csr<<<NBKT, 256, 0, stream>>>(bbase, ebuf, off, dinv, csr);

    // weight fragment split
    k_bsplit<<<16, 256, 0, stream>>>(Wi, 8, bfWi);
    k_bsplit<<<8, 256, 0, stream>>>(W1, 4, bfW1);
    k_bsplit<<<8, 256, 0, stream>>>(W2, 4, bfW2);

    // h1 = relu(x @ Wi + bi)           [bf16]
    k_gemm_x<DIM_IN><<<gM, 256, 0, stream>>>(x, bfWi, bi, bufA);
    // layer 1: t = (h1 @ W1) * dinv ; h2 = b1 + dinv*(self + gather)
    k_gemm_h<<<gM, 256, 0, stream>>>(bufA, bfW1, dinv, bufB);
    k_aggr_csr<<<gW, 256, 0, stream>>>(off, csr, bufB, dinv, b1, bufA);
    // layer 2
    k_gemm_h<<<gM, 256, 0, stream>>>(bufA, bfW2, dinv, bufB);
    k_aggr_csr<<<gW, 256, 0, stream>>>(off, csr, bufB, dinv, b2, bufA);

    k_head<<<gW, 256, 0, stream>>>(bufA, Wh, bh, out);
  } else {
    // fallback: fp32 atomic-scatter path (~103 MB)
    const int gN  = (N_NODES + 255) / 256;
    int*   off  = (int*)(ws + 4096);
    float* dinv = (float*)(ws + 404480);
    float* fbA  = (float*)(ws + 804864);
    float* fbB  = (float*)(ws + 804864 + (size_t)N_NODES * DIM_H * 4);
    const int gNH = (N_NODES * DIM_H + 255) / 256;
    const int gE2 = (N_EDGES + 1) / 2;
    k_zero<<<gN, 256, 0, stream>>>(off, N_NODES);
    k_count<<<gE, 256, 0, stream>>>(eidx, flag, off);
    k_dinv_old<<<gN, 256, 0, stream>>>(off, dinv);

    k_gemm<DIM_IN><<<gM, 256, 0, stream>>>(x, Wi, bi, nullptr, fbA, 1);
    k_gemm<DIM_H><<<gM, 256, 0, stream>>>(fbA, W1, nullptr, nullptr, fbB, 0);
    k_aggr_init<<<gNH, 256, 0, stream>>>(fbB, dinv, b1, fbA);
    k_aggr_edges<<<gE2, 256, 0, stream>>>(eidx, flag, fbB, dinv, fbA);
    k_gemm<DIM_H><<<gM, 256, 0, stream>>>(fbA, W2, nullptr, nullptr, fbB, 0);
    k_aggr_init<<<gNH, 256, 0, stream>>>(fbB, dinv, b2, fbA);
    k_aggr_edges<<<gE2, 256, 0, stream>>>(eidx, flag, fbB, dinv, fbA);
    k_head_f32<<<gW, 256, 0, stream>>>(fbA, Wh, bh, out);
  }
}

// Round 9
// 473.378 us; speedup vs baseline: 2.5111x; 2.5111x over previous
//
#include <hip/hip_runtime.h>
#include <hip/hip_bf16.h>

#define N_NODES 100000
#define N_EDGES 1600000
#define DIM_IN  256
#define DIM_H   128

#define NBKT 782          // ceil(N_NODES / 128) buckets of 128 nodes
#define CPAD 16           // ints per padded counter (one cacheline)
#define EPB  8192         // edges per build block
#define NBLK ((N_EDGES + EPB - 1) / EPB)   // 196

typedef __attribute__((ext_vector_type(8))) short short8;
typedef __attribute__((ext_vector_type(4))) float f32x4;

// ------------------------------------------------- edge_index width detect
__global__ __launch_bounds__(1024) void k_detect(const int* __restrict__ e,
                                                 int* __restrict__ flag) {
  __shared__ int s;
  if (threadIdx.x == 0) s = 0;
  __syncthreads();
  atomicOr(&s, e[2 * threadIdx.x + 1]);
  __syncthreads();
  if (threadIdx.x == 0) *flag = (s == 0) ? 1 : 0;
}

__device__ __forceinline__ int get_src(const int* e, int is64, int i) {
  return is64 ? e[2 * i] : e[i];
}
__device__ __forceinline__ int get_dst(const int* e, int is64, int i) {
  return is64 ? e[2 * (N_EDGES + i)] : e[N_EDGES + i];
}

__global__ __launch_bounds__(256) void k_zero(int* __restrict__ p, int n) {
  int i = blockIdx.x * 256 + threadIdx.x;
  if (i < n) p[i] = 0;
}

// ---------------------------------------------------- bucketed CSR build
// A: LDS-aggregated bucket histogram -> padded global counters
__global__ __launch_bounds__(1024)
void k_binc(const int* __restrict__ eidx, const int* __restrict__ flag,
            int* __restrict__ bcnt) {
  __shared__ int hist[NBKT];
  const int t = threadIdx.x;
  const int is64 = *flag;
  for (int i = t; i < NBKT; i += 1024) hist[i] = 0;
  __syncthreads();
#pragma unroll
  for (int j = 0; j < EPB / 1024; ++j) {
    int e = blockIdx.x * EPB + j * 1024 + t;
    if (e < N_EDGES) {
      unsigned s = (unsigned)get_src(eidx, is64, e);
      unsigned d = (unsigned)get_dst(eidx, is64, e);
      if (s < N_NODES && d < N_NODES) atomicAdd(&hist[d >> 7], 1);
    }
  }
  __syncthreads();
  for (int i = t; i < NBKT; i += 1024) {
    int h = hist[i];
    if (h) atomicAdd(&bcnt[i * CPAD], h);
  }
}

// B: scan padded counters -> bbase[0..NBKT] starts; reset counters to starts
__global__ __launch_bounds__(1024)
void k_bscan(int* __restrict__ bcnt, int* __restrict__ bbase) {
  __shared__ int sm[1024];
  int t = threadIdx.x;
  int v = (t < NBKT) ? bcnt[t * CPAD] : 0;
  sm[t] = v;
  __syncthreads();
  for (int d = 1; d < 1024; d <<= 1) {
    int u = (t >= d) ? sm[t - d] : 0;
    __syncthreads();
    sm[t] += u;
    __syncthreads();
  }
  if (t < NBKT) {
    int excl = sm[t] - v;
    bbase[t] = excl;
    bcnt[t * CPAD] = excl;
    if (t == NBKT - 1) bbase[NBKT] = sm[t];
  }
}

// C: scatter packed records into bucket regions, LDS-aggregated cursors
// record = src | (d&127)<<17   (src < 2^17)
__global__ __launch_bounds__(1024)
void k_bin(const int* __restrict__ eidx, const int* __restrict__ flag,
           int* __restrict__ bcnt, unsigned* __restrict__ ebuf) {
  __shared__ int hist[NBKT];
  __shared__ int cur[NBKT];
  const int t = threadIdx.x;
  const int is64 = *flag;
  for (int i = t; i < NBKT; i += 1024) hist[i] = 0;
  unsigned rec[EPB / 1024];
  int bkt[EPB / 1024];
  __syncthreads();
#pragma unroll
  for (int j = 0; j < EPB / 1024; ++j) {
    int e = blockIdx.x * EPB + j * 1024 + t;
    bkt[j] = -1;
    rec[j] = 0;
    if (e < N_EDGES) {
      unsigned s = (unsigned)get_src(eidx, is64, e);
      unsigned d = (unsigned)get_dst(eidx, is64, e);
      if (s < N_NODES && d < N_NODES) {
        bkt[j] = (int)(d >> 7);
        rec[j] = s | ((d & 127u) << 17);
        atomicAdd(&hist[bkt[j]], 1);
      }
    }
  }
  __syncthreads();
  for (int i = t; i < NBKT; i += 1024) {
    int h = hist[i];
    cur[i] = h ? atomicAdd(&bcnt[i * CPAD], h) : 0;
  }
  __syncthreads();
#pragma unroll
  for (int j = 0; j < EPB / 1024; ++j) {
    if (bkt[j] >= 0) {
      int pos = atomicAdd(&cur[bkt[j]], 1);
      ebuf[pos] = rec[j];
    }
  }
}

// D: per bucket -> node histogram, scan, write off (ends) + dinv + csr
__global__ __launch_bounds__(256)
void k_csr(const int* __restrict__ bbase, const unsigned* __restrict__ ebuf,
           int* __restrict__ off, float* __restrict__ dinv,
           int* __restrict__ csr) {
  __shared__ int hist[128];
  __shared__ int scn[128];
  __shared__ int cur[128];
  const int b = blockIdx.x, t = threadIdx.x;
  const int n0 = b << 7;
  const int start = bbase[b], end = bbase[b + 1];
  if (t < 128) hist[t] = 0;
  __syncthreads();
  for (int i = start + t; i < end; i += 256) {
    atomicAdd(&hist[ebuf[i] >> 17], 1);
  }
  __syncthreads();
  if (t < 128) scn[t] = hist[t];
  __syncthreads();
  for (int d = 1; d < 128; d <<= 1) {
    int u = (t < 128 && t >= d) ? scn[t - d] : 0;
    __syncthreads();
    if (t < 128) scn[t] += u;
    __syncthreads();
  }
  if (t < 128) {
    int node = n0 + t;
    if (node < N_NODES) {
      off[node] = start + scn[t];                    // ends
      dinv[node] = rsqrtf(1.0f + (float)hist[t]);
      cur[t] = start + scn[t] - hist[t];             // starts
    }
  }
  __syncthreads();
  for (int i = start + t; i < end; i += 256) {
    unsigned r = ebuf[i];
    int pos = atomicAdd(&cur[r >> 17], 1);
    csr[pos] = (int)(r & 0x1FFFFu);
  }
}

// ---------------------------------------------------------------- bf16 utils
__device__ __forceinline__ ushort f2bf(float f) {
  unsigned u = __float_as_uint(f);
  unsigned r = (u + 0x7fffu + ((u >> 16) & 1u)) >> 16;
  return (ushort)r;
}
__device__ __forceinline__ float bf2f(ushort h) {
  return __uint_as_float(((unsigned)h) << 16);
}
__device__ __forceinline__ float bflo(unsigned u) {
  return __uint_as_float(u << 16);
}
__device__ __forceinline__ float bfhi(unsigned u) {
  return __uint_as_float(u & 0xffff0000u);
}
__device__ __forceinline__ unsigned bfpack(float a, float b) {
  return (unsigned)f2bf(a) | ((unsigned)f2bf(b) << 16);
}

__device__ __forceinline__ void load8(const float* p, float* o) {
  float4 a = reinterpret_cast<const float4*>(p)[0];
  float4 b = reinterpret_cast<const float4*>(p)[1];
  o[0] = a.x; o[1] = a.y; o[2] = a.z; o[3] = a.w;
  o[4] = b.x; o[5] = b.y; o[6] = b.z; o[7] = b.w;
}

// Split weight W[K x 128] into MFMA B-fragment planes (hi, lo).
__global__ __launch_bounds__(256)
void k_bsplit(const float* __restrict__ W, const int CH, ushort* __restrict__ outHi) {
  int idx = blockIdx.x * 256 + threadIdx.x;
  if (idx >= CH * 512) return;
  int n  = idx & 15;
  int qq = (idx >> 4) & 3;
  int nt = (idx >> 6) & 7;
  int c  = idx >> 9;
  int col = nt * 16 + n;
  short8 h8, l8;
#pragma unroll
  for (int j = 0; j < 8; ++j) {
    float v = W[(size_t)(c * 32 + qq * 8 + j) * DIM_H + col];
    ushort hb = f2bf(v);
    ushort lb = f2bf(v - bf2f(hb));
    h8[j] = (short)hb;
    l8[j] = (short)lb;
  }
  ((short8*)outHi)[idx] = h8;
  ((short8*)outHi)[CH * 512 + idx] = l8;
}

// ------------------------------------- MFMA GEMM, fp32 A (split), bf16 out
template <int K>
__global__ __launch_bounds__(256)
void k_gemm_x(const float* __restrict__ A, const ushort* __restrict__ Bfrag,
              const float* __restrict__ bias, ushort* __restrict__ C) {
  constexpr int CH = K / 32;
  __shared__ __align__(16) ushort AhiS[256 * 8];
  __shared__ __align__(16) ushort AloS[256 * 8];
  const int tid = threadIdx.x;
  const int m0 = blockIdx.x * 64;
  const int wave = tid >> 6, lane = tid & 63;
  const int m_l = lane & 15, quad = lane >> 4;
  const int rs = tid >> 2, q = tid & 3;

  f32x4 acc[2][4];
#pragma unroll
  for (int i = 0; i < 2; ++i)
#pragma unroll
    for (int j = 0; j < 4; ++j) acc[i][j] = (f32x4){0.f, 0.f, 0.f, 0.f};

  const short8* Bhi8 = (const short8*)Bfrag;
  const short8* Blo8 = Bhi8 + CH * 512;
  short8* Ah8 = (short8*)AhiS;
  short8* Al8 = (short8*)AloS;

  for (int c = 0; c < CH; ++c) {
    float v[8];
    const int gm = m0 + rs;
    if (gm < N_NODES) {
      load8(&A[(size_t)gm * K + c * 32 + q * 8], v);
    } else {
#pragma unroll
      for (int j = 0; j < 8; ++j) v[j] = 0.f;
    }
    short8 h8, l8;
#pragma unroll
    for (int j = 0; j < 8; ++j) {
      ushort hb = f2bf(v[j]);
      ushort lb = f2bf(v[j] - bf2f(hb));
      h8[j] = (short)hb;
      l8[j] = (short)lb;
    }
    __syncthreads();
    const int ent = (rs >> 4) * 64 + q * 16 + (rs & 15);
    Ah8[ent] = h8;
    Al8[ent] = l8;
    __syncthreads();

    short8 ahi[4], alo[4];
#pragma unroll
    for (int mt = 0; mt < 4; ++mt) {
      ahi[mt] = Ah8[mt * 64 + quad * 16 + m_l];
      alo[mt] = Al8[mt * 64 + quad * 16 + m_l];
    }
#pragma unroll
    for (int ntl = 0; ntl < 2; ++ntl) {
      const int bent = ((c * 8 + wave * 2 + ntl) * 4 + quad) * 16 + m_l;
      short8 bhi = Bhi8[bent];
      short8 blo = Blo8[bent];
#pragma unroll
      for (int mt = 0; mt < 4; ++mt) {
        acc[ntl][mt] = __builtin_amdgcn_mfma_f32_16x16x32_bf16(ahi[mt], bhi, acc[ntl][mt], 0, 0, 0);
        acc[ntl][mt] = __builtin_amdgcn_mfma_f32_16x16x32_bf16(ahi[mt], blo, acc[ntl][mt], 0, 0, 0);
        acc[ntl][mt] = __builtin_amdgcn_mfma_f32_16x16x32_bf16(alo[mt], bhi, acc[ntl][mt], 0, 0, 0);
      }
    }
  }

#pragma unroll
  for (int ntl = 0; ntl < 2; ++ntl) {
    const int colg = (wave * 2 + ntl) * 16 + m_l;
    const float bv = bias[colg];
#pragma unroll
    for (int mt = 0; mt < 4; ++mt) {
#pragma unroll
      for (int r = 0; r < 4; ++r) {
        const int rowg = m0 + mt * 16 + quad * 4 + r;
        if (rowg < N_NODES) {
          float t = fmaxf(acc[ntl][mt][r] + bv, 0.f);  // relu
          C[(size_t)rowg * DIM_H + colg] = f2bf(t);
        }
      }
    }
  }
}

// ------------------------------------- MFMA GEMM, bf16 A, bf16 out, row scale
__global__ __launch_bounds__(256)
void k_gemm_h(const ushort* __restrict__ A, const ushort* __restrict__ Bfrag,
              const float* __restrict__ scale, ushort* __restrict__ C) {
  constexpr int K = DIM_H, CH = K / 32;
  __shared__ __align__(16) ushort AS[256 * 8];
  const int tid = threadIdx.x;
  const int m0 = blockIdx.x * 64;
  const int wave = tid >> 6, lane = tid & 63;
  const int m_l = lane & 15, quad = lane >> 4;
  const int rs = tid >> 2, q = tid & 3;

  f32x4 acc[2][4];
#pragma unroll
  for (int i = 0; i < 2; ++i)
#pragma unroll
    for (int j = 0; j < 4; ++j) acc[i][j] = (f32x4){0.f, 0.f, 0.f, 0.f};

  const short8* Bhi8 = (const short8*)Bfrag;
  const short8* Blo8 = Bhi8 + CH * 512;
  short8* A8 = (short8*)AS;

#pragma unroll
  for (int c = 0; c < CH; ++c) {
    short8 h8 = {0, 0, 0, 0, 0, 0, 0, 0};
    const int gm = m0 + rs;
    if (gm < N_NODES)
      h8 = *reinterpret_cast<const short8*>(&A[(size_t)gm * DIM_H + c * 32 + q * 8]);
    __syncthreads();
    A8[(rs >> 4) * 64 + q * 16 + (rs & 15)] = h8;
    __syncthreads();

    short8 a[4];
#pragma unroll
    for (int mt = 0; mt < 4; ++mt) a[mt] = A8[mt * 64 + quad * 16 + m_l];
#pragma unroll
    for (int ntl = 0; ntl < 2; ++ntl) {
      const int bent = ((c * 8 + wave * 2 + ntl) * 4 + quad) * 16 + m_l;
      short8 bhi = Bhi8[bent];
      short8 blo = Blo8[bent];
#pragma unroll
      for (int mt = 0; mt < 4; ++mt) {
        acc[ntl][mt] = __builtin_amdgcn_mfma_f32_16x16x32_bf16(a[mt], bhi, acc[ntl][mt], 0, 0, 0);
        acc[ntl][mt] = __builtin_amdgcn_mfma_f32_16x16x32_bf16(a[mt], blo, acc[ntl][mt], 0, 0, 0);
      }
    }
  }

#pragma unroll
  for (int ntl = 0; ntl < 2; ++ntl) {
    const int colg = (wave * 2 + ntl) * 16 + m_l;
#pragma unroll
    for (int mt = 0; mt < 4; ++mt) {
#pragma unroll
      for (int r = 0; r < 4; ++r) {
        const int rowg = m0 + mt * 16 + quad * 4 + r;
        if (rowg < N_NODES)
          C[(size_t)rowg * DIM_H + colg] = f2bf(acc[ntl][mt][r] * scale[rowg]);
      }
    }
  }
}

// ---------------------------------------------------------------- CSR gather
__global__ __launch_bounds__(256)
void k_aggr_csr(const int* __restrict__ off, const int* __restrict__ csr,
                const ushort* __restrict__ t, const float* __restrict__ dinv,
                const float* __restrict__ bias, ushort* __restrict__ h) {
  int node = blockIdx.x * 4 + (threadIdx.x >> 6);
  if (node >= N_NODES) return;
  int lane = threadIdx.x & 63;
  const unsigned* tu = (const unsigned*)t;
  int start = (node == 0) ? 0 : off[node - 1];
  int end = off[node];
  unsigned su = tu[(size_t)node * 64 + lane];
  float ax = bflo(su), ay = bfhi(su);
  int e = start;
  for (; e + 3 < end; e += 4) {
    int s0 = csr[e], s1 = csr[e + 1], s2 = csr[e + 2], s3 = csr[e + 3];
    unsigned u0 = tu[(size_t)s0 * 64 + lane];
    unsigned u1 = tu[(size_t)s1 * 64 + lane];
    unsigned u2 = tu[(size_t)s2 * 64 + lane];
    unsigned u3 = tu[(size_t)s3 * 64 + lane];
    ax += (bflo(u0) + bflo(u1)) + (bflo(u2) + bflo(u3));
    ay += (bfhi(u0) + bfhi(u1)) + (bfhi(u2) + bfhi(u3));
  }
  for (; e < end; ++e) {
    unsigned u0 = tu[(size_t)csr[e] * 64 + lane];
    ax += bflo(u0);
    ay += bfhi(u0);
  }
  float dn = dinv[node];
  float2 b = ((const float2*)bias)[lane];
  ((unsigned*)h)[(size_t)node * 64 + lane] = bfpack(b.x + dn * ax, b.y + dn * ay);
}

// ---------------------------------------------------------------- head
__global__ __launch_bounds__(256)
void k_head(const ushort* __restrict__ h, const float* __restrict__ Wh,
            const float* __restrict__ bh, float* __restrict__ out) {
  int node = blockIdx.x * 4 + (threadIdx.x >> 6);
  int lane = threadIdx.x & 63;
  if (node >= N_NODES) return;
  unsigned u = ((const unsigned*)h)[(size_t)node * 64 + lane];
  float f0 = bflo(u), f1 = bfhi(u);
  float s0 = f0 * Wh[4 * lane + 0] + f1 * Wh[4 * lane + 2];
  float s1 = f0 * Wh[4 * lane + 1] + f1 * Wh[4 * lane + 3];
#pragma unroll
  for (int off = 32; off > 0; off >>= 1) {
    s0 += __shfl_down(s0, off);
    s1 += __shfl_down(s1, off);
  }
  if (lane == 0) {
    reinterpret_cast<float2*>(out)[node] = make_float2(s0 + bh[0], s1 + bh[1]);
  }
}

// --------------------------------------------- fp32 fallback (small ws) ----
__global__ __launch_bounds__(256) void k_count(const int* __restrict__ eidx,
                                               const int* __restrict__ flag,
                                               int* __restrict__ off) {
  int e = blockIdx.x * 256 + threadIdx.x;
  int is64 = *flag;
  if (e < N_EDGES) {
    unsigned d = (unsigned)get_dst(eidx, is64, e);
    if (d < N_NODES) atomicAdd(&off[d], 1);
  }
}

__global__ __launch_bounds__(256) void k_dinv_old(const int* __restrict__ off,
                                                  float* __restrict__ dinv) {
  int i = blockIdx.x * 256 + threadIdx.x;
  if (i < N_NODES) dinv[i] = rsqrtf(1.0f + (float)off[i]);
}

template <int K>
__global__ __launch_bounds__(256)
void k_gemm(const float* __restrict__ A, const float* __restrict__ B,
            const float* __restrict__ bias, const float* __restrict__ scale,
            float* __restrict__ C, const int do_relu) {
  __shared__ float As[64][33];
  const int tid = threadIdx.x;
  const int tx = tid & 15;
  const int ty = tid >> 4;
  const int m0 = blockIdx.x * 64;

  float acc[4][8];
#pragma unroll
  for (int i = 0; i < 4; ++i)
#pragma unroll
    for (int j = 0; j < 8; ++j) acc[i][j] = 0.f;

  const int rs = tid >> 2;
  const int ks = (tid & 3) * 8;

  for (int k0 = 0; k0 < K; k0 += 32) {
    float av8[8];
    const int gm = m0 + rs;
    if (gm < N_NODES) {
      load8(&A[(size_t)gm * K + k0 + ks], av8);
    } else {
#pragma unroll
      for (int j = 0; j < 8; ++j) av8[j] = 0.f;
    }
    __syncthreads();
#pragma unroll
    for (int j = 0; j < 8; ++j) As[rs][ks + j] = av8[j];
    __syncthreads();

    const float* Bp = B + (size_t)k0 * DIM_H + tx * 8;
#pragma unroll 4
    for (int k = 0; k < 32; ++k) {
      float bv[8];
      load8(Bp + (size_t)k * DIM_H, bv);
      float av[4];
#pragma unroll
      for (int rr = 0; rr < 4; ++rr) av[rr] = As[ty * 4 + rr][k];
#pragma unroll
      for (int rr = 0; rr < 4; ++rr)
#pragma unroll
        for (int cc = 0; cc < 8; ++cc)
          acc[rr][cc] = fmaf(av[rr], bv[cc], acc[rr][cc]);
    }
  }

  float bs[8];
  if (bias) {
    load8(bias + tx * 8, bs);
  } else {
#pragma unroll
    for (int j = 0; j < 8; ++j) bs[j] = 0.f;
  }
#pragma unroll
  for (int rr = 0; rr < 4; ++rr) {
    const int gm = m0 + ty * 4 + rr;
    if (gm < N_NODES) {
      float sc = scale ? scale[gm] : 1.0f;
      float v[8];
#pragma unroll
      for (int cc = 0; cc < 8; ++cc) {
        float t = acc[rr][cc] + bs[cc];
        if (do_relu) t = fmaxf(t, 0.f);
        v[cc] = t * sc;
      }
      float* Cp = &C[(size_t)gm * DIM_H + tx * 8];
      reinterpret_cast<float4*>(Cp)[0] = make_float4(v[0], v[1], v[2], v[3]);
      reinterpret_cast<float4*>(Cp)[1] = make_float4(v[4], v[5], v[6], v[7]);
    }
  }
}

__global__ __launch_bounds__(256)
void k_aggr_init(const float* __restrict__ t, const float* __restrict__ dinv,
                 const float* __restrict__ bias, float* __restrict__ h) {
  int idx = blockIdx.x * 256 + threadIdx.x;
  if (idx < N_NODES * DIM_H) {
    int i = idx >> 7;
    int c = idx & 127;
    float d = dinv[i];
    h[idx] = bias[c] + t[idx] * d * d;
  }
}

__global__ __launch_bounds__(256)
void k_aggr_edges(const int* __restrict__ eidx, const int* __restrict__ flag,
                  const float* __restrict__ t, const float* __restrict__ dinv,
                  float* __restrict__ h) {
  int e = blockIdx.x * 2 + (threadIdx.x >> 7);
  int c = threadIdx.x & 127;
  int is64 = *flag;
  if (e < N_EDGES) {
    unsigned s = (unsigned)get_src(eidx, is64, e);
    unsigned d = (unsigned)get_dst(eidx, is64, e);
    if (s < N_NODES && d < N_NODES) {
      float nrm = dinv[s] * dinv[d];
      unsafeAtomicAdd(&h[(size_t)d * DIM_H + c], t[(size_t)s * DIM_H + c] * nrm);
    }
  }
}

__global__ __launch_bounds__(256)
void k_head_f32(const float* __restrict__ h, const float* __restrict__ Wh,
                const float* __restrict__ bh, float* __restrict__ out) {
  int node = blockIdx.x * 4 + (threadIdx.x >> 6);
  int lane = threadIdx.x & 63;
  if (node >= N_NODES) return;
  float h0 = h[(size_t)node * DIM_H + lane];
  float h1 = h[(size_t)node * DIM_H + 64 + lane];
  float s0 = h0 * Wh[lane * 2 + 0] + h1 * Wh[(lane + 64) * 2 + 0];
  float s1 = h0 * Wh[lane * 2 + 1] + h1 * Wh[(lane + 64) * 2 + 1];
#pragma unroll
  for (int off = 32; off > 0; off >>= 1) {
    s0 += __shfl_down(s0, off);
    s1 += __shfl_down(s1, off);
  }
  if (lane == 0) {
    reinterpret_cast<float2*>(out)[node] = make_float2(s0 + bh[0], s1 + bh[1]);
  }
}

// ---------------------------------------------------------------- launch
extern "C" void kernel_launch(void* const* d_in, const int* in_sizes, int n_in,
                              void* d_out, int out_size, void* d_ws, size_t ws_size,
                              hipStream_t stream) {
  (void)in_sizes; (void)n_in; (void)out_size;
  const int* eidx = (const int*)d_in[0];
  const float* x  = (const float*)d_in[1];
  const float* Wi = (const float*)d_in[2];
  const float* bi = (const float*)d_in[3];
  const float* W1 = (const float*)d_in[4];
  const float* b1 = (const float*)d_in[5];
  const float* W2 = (const float*)d_in[6];
  const float* b2 = (const float*)d_in[7];
  const float* Wh = (const float*)d_in[8];
  const float* bh = (const float*)d_in[9];
  float* out = (float*)d_out;

  const int gE  = (N_EDGES + 255) / 256;
  const int gM  = (N_NODES + 63) / 64;
  const int gW  = (N_NODES + 3) / 4;

  char* ws = (char*)d_ws;
  int* flag = (int*)ws;
  k_detect<<<1, 1024, 0, stream>>>(eidx, flag);

  // tier 1 layout (ends at 65,128,448 B):
  // flag@0 | bcnt@4096 (782*16 ints, padded) | bbase@57344 (783) |
  // bfWi@65536 (128K) | bfW1@196608 (64K) | bfW2@262144 (64K) |
  // off@327680 | dinv@728064 | csr@1128448 (6.4M) | ebuf@7528448 (6.4M) |
  // bufA@13928448 (25.6M) | bufB@39528448 (25.6M)
  const size_t need1 = 65128448;

  if (ws_size >= need1) {
    int*      bcnt  = (int*)(ws + 4096);
    int*      bbase = (int*)(ws + 57344);
    ushort*   bfWi  = (ushort*)(ws + 65536);
    ushort*   bfW1  = (ushort*)(ws + 196608);
    ushort*   bfW2  = (ushort*)(ws + 262144);
    int*      off   = (int*)(ws + 327680);
    float*    dinv  = (float*)(ws + 728064);
    int*      csr   = (int*)(ws + 1128448);
    unsigned* ebuf  = (unsigned*)(ws + 7528448);
    ushort*   bufA  = (ushort*)(ws + 13928448);
    ushort*   bufB  = (ushort*)(ws + 39528448);

    // bucketed CSR build (LDS-aggregated, padded counters)
    k_zero<<<(NBKT * CPAD + 255) / 256, 256, 0, stream>>>(bcnt, NBKT * CPAD);
    k_binc<<<NBLK, 1024, 0, stream>>>(eidx, flag, bcnt);
    k_bscan<<<1, 1024, 0, stream>>>(bcnt, bbase);
    k_bin<<<NBLK, 1024, 0, stream>>>(eidx, flag, bcnt, ebuf);
    k_csr<<<NBKT, 256, 0, stream>>>(bbase, ebuf, off, dinv, csr);

    // weight fragment split
    k_bsplit<<<16, 256, 0, stream>>>(Wi, 8, bfWi);
    k_bsplit<<<8, 256, 0, stream>>>(W1, 4, bfW1);
    k_bsplit<<<8, 256, 0, stream>>>(W2, 4, bfW2);

    // h1 = relu(x @ Wi + bi)           [bf16]
    k_gemm_x<DIM_IN><<<gM, 256, 0, stream>>>(x, bfWi, bi, bufA);
    // layer 1: t = (h1 @ W1) * dinv ; h2 = b1 + dinv*(self + gather)
    k_gemm_h<<<gM, 256, 0, stream>>>(bufA, bfW1, dinv, bufB);
    k_aggr_csr<<<gW, 256, 0, stream>>>(off, csr, bufB, dinv, b1, bufA);
    // layer 2
    k_gemm_h<<<gM, 256, 0, stream>>>(bufA, bfW2, dinv, bufB);
    k_aggr_csr<<<gW, 256, 0, stream>>>(off, csr, bufB, dinv, b2, bufA);

    k_head<<<gW, 256, 0, stream>>>(bufA, Wh, bh, out);
  } else {
    // fallback: fp32 atomic-scatter path (~103 MB)
    const int gN  = (N_NODES + 255) / 256;
    int*   off  = (int*)(ws + 4096);
    float* dinv = (float*)(ws + 404480);
    float* fbA  = (float*)(ws + 804864);
    float* fbB  = (float*)(ws + 804864 + (size_t)N_NODES * DIM_H * 4);
    const int gNH = (N_NODES * DIM_H + 255) / 256;
    const int gE2 = (N_EDGES + 1) / 2;
    k_zero<<<gN, 256, 0, stream>>>(off, N_NODES);
    k_count<<<gE, 256, 0, stream>>>(eidx, flag, off);
    k_dinv_old<<<gN, 256, 0, stream>>>(off, dinv);

    k_gemm<DIM_IN><<<gM, 256, 0, stream>>>(x, Wi, bi, nullptr, fbA, 1);
    k_gemm<DIM_H><<<gM, 256, 0, stream>>>(fbA, W1, nullptr, nullptr, fbB, 0);
    k_aggr_init<<<gNH, 256, 0, stream>>>(fbB, dinv, b1, fbA);
    k_aggr_edges<<<gE2, 256, 0, stream>>>(eidx, flag, fbB, dinv, fbA);
    k_gemm<DIM_H><<<gM, 256, 0, stream>>>(fbA, W2, nullptr, nullptr, fbB, 0);
    k_aggr_init<<<gNH, 256, 0, stream>>>(fbB, dinv, b2, fbA);
    k_aggr_edges<<<gE2, 256, 0, stream>>>(eidx, flag, fbB, dinv, fbA);
    k_head_f32<<<gW, 256, 0, stream>>>(fbA, Wh, bh, out);
  }
}

// Round 10
// 452.800 us; speedup vs baseline: 2.6252x; 1.0454x over previous
//
#include <hip/hip_runtime.h>
#include <hip/hip_bf16.h>

#define N_NODES 100000
#define N_EDGES 1600000
#define DIM_IN  256
#define DIM_H   128

#define NBKT 782          // ceil(N_NODES / 128) buckets of 128 nodes
#define CPAD 16           // ints per padded counter (one cacheline)
#define EPB  8192         // edges per build block
#define NBLK ((N_EDGES + EPB - 1) / EPB)   // 196

typedef __attribute__((ext_vector_type(8))) short short8;
typedef __attribute__((ext_vector_type(4))) float f32x4;

// ------------------------------------------------- edge_index width detect
__global__ __launch_bounds__(1024) void k_detect(const int* __restrict__ e,
                                                 int* __restrict__ flag) {
  __shared__ int s;
  if (threadIdx.x == 0) s = 0;
  __syncthreads();
  atomicOr(&s, e[2 * threadIdx.x + 1]);
  __syncthreads();
  if (threadIdx.x == 0) *flag = (s == 0) ? 1 : 0;
}

__device__ __forceinline__ int get_src(const int* e, int is64, int i) {
  return is64 ? e[2 * i] : e[i];
}
__device__ __forceinline__ int get_dst(const int* e, int is64, int i) {
  return is64 ? e[2 * (N_EDGES + i)] : e[N_EDGES + i];
}

__global__ __launch_bounds__(256) void k_zero(int* __restrict__ p, int n) {
  int i = blockIdx.x * 256 + threadIdx.x;
  if (i < n) p[i] = 0;
}

// ---------------------------------------------------- bucketed CSR build
__global__ __launch_bounds__(1024)
void k_binc(const int* __restrict__ eidx, const int* __restrict__ flag,
            int* __restrict__ bcnt) {
  __shared__ int hist[NBKT];
  const int t = threadIdx.x;
  const int is64 = *flag;
  for (int i = t; i < NBKT; i += 1024) hist[i] = 0;
  __syncthreads();
#pragma unroll
  for (int j = 0; j < EPB / 1024; ++j) {
    int e = blockIdx.x * EPB + j * 1024 + t;
    if (e < N_EDGES) {
      unsigned s = (unsigned)get_src(eidx, is64, e);
      unsigned d = (unsigned)get_dst(eidx, is64, e);
      if (s < N_NODES && d < N_NODES) atomicAdd(&hist[d >> 7], 1);
    }
  }
  __syncthreads();
  for (int i = t; i < NBKT; i += 1024) {
    int h = hist[i];
    if (h) atomicAdd(&bcnt[i * CPAD], h);
  }
}

__global__ __launch_bounds__(1024)
void k_bscan(int* __restrict__ bcnt, int* __restrict__ bbase) {
  __shared__ int sm[1024];
  int t = threadIdx.x;
  int v = (t < NBKT) ? bcnt[t * CPAD] : 0;
  sm[t] = v;
  __syncthreads();
  for (int d = 1; d < 1024; d <<= 1) {
    int u = (t >= d) ? sm[t - d] : 0;
    __syncthreads();
    sm[t] += u;
    __syncthreads();
  }
  if (t < NBKT) {
    int excl = sm[t] - v;
    bbase[t] = excl;
    bcnt[t * CPAD] = excl;
    if (t == NBKT - 1) bbase[NBKT] = sm[t];
  }
}

// record = src | (d&127)<<17   (src < 2^17)
__global__ __launch_bounds__(1024)
void k_bin(const int* __restrict__ eidx, const int* __restrict__ flag,
           int* __restrict__ bcnt, unsigned* __restrict__ ebuf) {
  __shared__ int hist[NBKT];
  __shared__ int cur[NBKT];
  const int t = threadIdx.x;
  const int is64 = *flag;
  for (int i = t; i < NBKT; i += 1024) hist[i] = 0;
  unsigned rec[EPB / 1024];
  int bkt[EPB / 1024];
  __syncthreads();
#pragma unroll
  for (int j = 0; j < EPB / 1024; ++j) {
    int e = blockIdx.x * EPB + j * 1024 + t;
    bkt[j] = -1;
    rec[j] = 0;
    if (e < N_EDGES) {
      unsigned s = (unsigned)get_src(eidx, is64, e);
      unsigned d = (unsigned)get_dst(eidx, is64, e);
      if (s < N_NODES && d < N_NODES) {
        bkt[j] = (int)(d >> 7);
        rec[j] = s | ((d & 127u) << 17);
        atomicAdd(&hist[bkt[j]], 1);
      }
    }
  }
  __syncthreads();
  for (int i = t; i < NBKT; i += 1024) {
    int h = hist[i];
    cur[i] = h ? atomicAdd(&bcnt[i * CPAD], h) : 0;
  }
  __syncthreads();
#pragma unroll
  for (int j = 0; j < EPB / 1024; ++j) {
    if (bkt[j] >= 0) {
      int pos = atomicAdd(&cur[bkt[j]], 1);
      ebuf[pos] = rec[j];
    }
  }
}

__global__ __launch_bounds__(256)
void k_csr(const int* __restrict__ bbase, const unsigned* __restrict__ ebuf,
           int* __restrict__ off, float* __restrict__ dinv,
           int* __restrict__ csr) {
  __shared__ int hist[128];
  __shared__ int scn[128];
  __shared__ int cur[128];
  const int b = blockIdx.x, t = threadIdx.x;
  const int n0 = b << 7;
  const int start = bbase[b], end = bbase[b + 1];
  if (t < 128) hist[t] = 0;
  __syncthreads();
  for (int i = start + t; i < end; i += 256) {
    atomicAdd(&hist[ebuf[i] >> 17], 1);
  }
  __syncthreads();
  if (t < 128) scn[t] = hist[t];
  __syncthreads();
  for (int d = 1; d < 128; d <<= 1) {
    int u = (t < 128 && t >= d) ? scn[t - d] : 0;
    __syncthreads();
    if (t < 128) scn[t] += u;
    __syncthreads();
  }
  if (t < 128) {
    int node = n0 + t;
    if (node < N_NODES) {
      off[node] = start + scn[t];                    // ends
      dinv[node] = rsqrtf(1.0f + (float)hist[t]);
      cur[t] = start + scn[t] - hist[t];             // starts
    }
  }
  __syncthreads();
  for (int i = start + t; i < end; i += 256) {
    unsigned r = ebuf[i];
    int pos = atomicAdd(&cur[r >> 17], 1);
    csr[pos] = (int)(r & 0x1FFFFu);
  }
}

// ---------------------------------------------------------------- bf16 utils
__device__ __forceinline__ ushort f2bf(float f) {
  unsigned u = __float_as_uint(f);
  unsigned r = (u + 0x7fffu + ((u >> 16) & 1u)) >> 16;
  return (ushort)r;
}
__device__ __forceinline__ float bf2f(ushort h) {
  return __uint_as_float(((unsigned)h) << 16);
}
__device__ __forceinline__ float bflo(unsigned u) {
  return __uint_as_float(u << 16);
}
__device__ __forceinline__ float bfhi(unsigned u) {
  return __uint_as_float(u & 0xffff0000u);
}
__device__ __forceinline__ unsigned bfpack(float a, float b) {
  return (unsigned)f2bf(a) | ((unsigned)f2bf(b) << 16);
}

__device__ __forceinline__ void load8(const float* p, float* o) {
  float4 a = reinterpret_cast<const float4*>(p)[0];
  float4 b = reinterpret_cast<const float4*>(p)[1];
  o[0] = a.x; o[1] = a.y; o[2] = a.z; o[3] = a.w;
  o[4] = b.x; o[5] = b.y; o[6] = b.z; o[7] = b.w;
}

// Split weight W[K x 128] into MFMA B-fragment planes (hi, lo).
__global__ __launch_bounds__(256)
void k_bsplit(const float* __restrict__ W, const int CH, ushort* __restrict__ outHi) {
  int idx = blockIdx.x * 256 + threadIdx.x;
  if (idx >= CH * 512) return;
  int n  = idx & 15;
  int qq = (idx >> 4) & 3;
  int nt = (idx >> 6) & 7;
  int c  = idx >> 9;
  int col = nt * 16 + n;
  short8 h8, l8;
#pragma unroll
  for (int j = 0; j < 8; ++j) {
    float v = W[(size_t)(c * 32 + qq * 8 + j) * DIM_H + col];
    ushort hb = f2bf(v);
    ushort lb = f2bf(v - bf2f(hb));
    h8[j] = (short)hb;
    l8[j] = (short)lb;
  }
  ((short8*)outHi)[idx] = h8;
  ((short8*)outHi)[CH * 512 + idx] = l8;
}

// ------------------------------------- MFMA GEMM, fp32 A (split), bf16 out
template <int K>
__global__ __launch_bounds__(256)
void k_gemm_x(const float* __restrict__ A, const ushort* __restrict__ Bfrag,
              const float* __restrict__ bias, ushort* __restrict__ C) {
  constexpr int CH = K / 32;
  __shared__ __align__(16) ushort AhiS[256 * 8];
  __shared__ __align__(16) ushort AloS[256 * 8];
  const int tid = threadIdx.x;
  const int m0 = blockIdx.x * 64;
  const int wave = tid >> 6, lane = tid & 63;
  const int m_l = lane & 15, quad = lane >> 4;
  const int rs = tid >> 2, q = tid & 3;

  f32x4 acc[2][4];
#pragma unroll
  for (int i = 0; i < 2; ++i)
#pragma unroll
    for (int j = 0; j < 4; ++j) acc[i][j] = (f32x4){0.f, 0.f, 0.f, 0.f};

  const short8* Bhi8 = (const short8*)Bfrag;
  const short8* Blo8 = Bhi8 + CH * 512;
  short8* Ah8 = (short8*)AhiS;
  short8* Al8 = (short8*)AloS;

  for (int c = 0; c < CH; ++c) {
    float v[8];
    const int gm = m0 + rs;
    if (gm < N_NODES) {
      load8(&A[(size_t)gm * K + c * 32 + q * 8], v);
    } else {
#pragma unroll
      for (int j = 0; j < 8; ++j) v[j] = 0.f;
    }
    short8 h8, l8;
#pragma unroll
    for (int j = 0; j < 8; ++j) {
      ushort hb = f2bf(v[j]);
      ushort lb = f2bf(v[j] - bf2f(hb));
      h8[j] = (short)hb;
      l8[j] = (short)lb;
    }
    __syncthreads();
    const int ent = (rs >> 4) * 64 + q * 16 + (rs & 15);
    Ah8[ent] = h8;
    Al8[ent] = l8;
    __syncthreads();

    short8 ahi[4], alo[4];
#pragma unroll
    for (int mt = 0; mt < 4; ++mt) {
      ahi[mt] = Ah8[mt * 64 + quad * 16 + m_l];
      alo[mt] = Al8[mt * 64 + quad * 16 + m_l];
    }
#pragma unroll
    for (int ntl = 0; ntl < 2; ++ntl) {
      const int bent = ((c * 8 + wave * 2 + ntl) * 4 + quad) * 16 + m_l;
      short8 bhi = Bhi8[bent];
      short8 blo = Blo8[bent];
#pragma unroll
      for (int mt = 0; mt < 4; ++mt) {
        acc[ntl][mt] = __builtin_amdgcn_mfma_f32_16x16x32_bf16(ahi[mt], bhi, acc[ntl][mt], 0, 0, 0);
        acc[ntl][mt] = __builtin_amdgcn_mfma_f32_16x16x32_bf16(ahi[mt], blo, acc[ntl][mt], 0, 0, 0);
        acc[ntl][mt] = __builtin_amdgcn_mfma_f32_16x16x32_bf16(alo[mt], bhi, acc[ntl][mt], 0, 0, 0);
      }
    }
  }

#pragma unroll
  for (int ntl = 0; ntl < 2; ++ntl) {
    const int colg = (wave * 2 + ntl) * 16 + m_l;
    const float bv = bias[colg];
#pragma unroll
    for (int mt = 0; mt < 4; ++mt) {
#pragma unroll
      for (int r = 0; r < 4; ++r) {
        const int rowg = m0 + mt * 16 + quad * 4 + r;
        if (rowg < N_NODES) {
          float t = fmaxf(acc[ntl][mt][r] + bv, 0.f);  // relu
          C[(size_t)rowg * DIM_H + colg] = f2bf(t);
        }
      }
    }
  }
}

// ------------------------------------- MFMA GEMM, bf16 A, bf16 out, row scale
__global__ __launch_bounds__(256)
void k_gemm_h(const ushort* __restrict__ A, const ushort* __restrict__ Bfrag,
              const float* __restrict__ scale, ushort* __restrict__ C) {
  constexpr int K = DIM_H, CH = K / 32;
  __shared__ __align__(16) ushort AS[256 * 8];
  const int tid = threadIdx.x;
  const int m0 = blockIdx.x * 64;
  const int wave = tid >> 6, lane = tid & 63;
  const int m_l = lane & 15, quad = lane >> 4;
  const int rs = tid >> 2, q = tid & 3;

  f32x4 acc[2][4];
#pragma unroll
  for (int i = 0; i < 2; ++i)
#pragma unroll
    for (int j = 0; j < 4; ++j) acc[i][j] = (f32x4){0.f, 0.f, 0.f, 0.f};

  const short8* Bhi8 = (const short8*)Bfrag;
  const short8* Blo8 = Bhi8 + CH * 512;
  short8* A8 = (short8*)AS;

#pragma unroll
  for (int c = 0; c < CH; ++c) {
    short8 h8 = {0, 0, 0, 0, 0, 0, 0, 0};
    const int gm = m0 + rs;
    if (gm < N_NODES)
      h8 = *reinterpret_cast<const short8*>(&A[(size_t)gm * DIM_H + c * 32 + q * 8]);
    __syncthreads();
    A8[(rs >> 4) * 64 + q * 16 + (rs & 15)] = h8;
    __syncthreads();

    short8 a[4];
#pragma unroll
    for (int mt = 0; mt < 4; ++mt) a[mt] = A8[mt * 64 + quad * 16 + m_l];
#pragma unroll
    for (int ntl = 0; ntl < 2; ++ntl) {
      const int bent = ((c * 8 + wave * 2 + ntl) * 4 + quad) * 16 + m_l;
      short8 bhi = Bhi8[bent];
      short8 blo = Blo8[bent];
#pragma unroll
      for (int mt = 0; mt < 4; ++mt) {
        acc[ntl][mt] = __builtin_amdgcn_mfma_f32_16x16x32_bf16(a[mt], bhi, acc[ntl][mt], 0, 0, 0);
        acc[ntl][mt] = __builtin_amdgcn_mfma_f32_16x16x32_bf16(a[mt], blo, acc[ntl][mt], 0, 0, 0);
      }
    }
  }

#pragma unroll
  for (int ntl = 0; ntl < 2; ++ntl) {
    const int colg = (wave * 2 + ntl) * 16 + m_l;
#pragma unroll
    for (int mt = 0; mt < 4; ++mt) {
#pragma unroll
      for (int r = 0; r < 4; ++r) {
        const int rowg = m0 + mt * 16 + quad * 4 + r;
        if (rowg < N_NODES)
          C[(size_t)rowg * DIM_H + colg] = f2bf(acc[ntl][mt][r] * scale[rowg]);
      }
    }
  }
}

// ------------------------------------------- CSR gather, dual-half ILP
// wave = 2 interleaved edge streams; lane covers 4 bf16 cols via uint2.
// h[i] = bias + dinv[i]*(t[i] + sum t[s]), bf16 out.
__global__ __launch_bounds__(256)
void k_aggr_csr(const int* __restrict__ off, const int* __restrict__ csr,
                const ushort* __restrict__ t, const float* __restrict__ dinv,
                const float* __restrict__ bias, ushort* __restrict__ h) {
  int node = blockIdx.x * 4 + (threadIdx.x >> 6);
  if (node >= N_NODES) return;
  const int lane = threadIdx.x & 63;
  const int half = lane >> 5;      // edge-stream parity
  const int col = lane & 31;       // uint2 column (4 bf16)
  const uint2* t2 = (const uint2*)t;
  int start = (node == 0) ? 0 : off[node - 1];
  int end = off[node];
  float a0 = 0.f, a1 = 0.f, a2 = 0.f, a3 = 0.f;
  if (half == 0) {  // self term once
    uint2 u = t2[(size_t)node * 32 + col];
    a0 = bflo(u.x); a1 = bfhi(u.x); a2 = bflo(u.y); a3 = bfhi(u.y);
  }
  int e = start + half;
  for (; e + 6 < end; e += 8) {
    int s0 = csr[e], s1 = csr[e + 2], s2 = csr[e + 4], s3 = csr[e + 6];
    uint2 u0 = t2[(size_t)s0 * 32 + col];
    uint2 u1 = t2[(size_t)s1 * 32 + col];
    uint2 u2 = t2[(size_t)s2 * 32 + col];
    uint2 u3 = t2[(size_t)s3 * 32 + col];
    a0 += (bflo(u0.x) + bflo(u1.x)) + (bflo(u2.x) + bflo(u3.x));
    a1 += (bfhi(u0.x) + bfhi(u1.x)) + (bfhi(u2.x) + bfhi(u3.x));
    a2 += (bflo(u0.y) + bflo(u1.y)) + (bflo(u2.y) + bflo(u3.y));
    a3 += (bfhi(u0.y) + bfhi(u1.y)) + (bfhi(u2.y) + bfhi(u3.y));
  }
  for (; e < end; e += 2) {
    uint2 u = t2[(size_t)csr[e] * 32 + col];
    a0 += bflo(u.x); a1 += bfhi(u.x); a2 += bflo(u.y); a3 += bfhi(u.y);
  }
  // combine the two halves (lanes l and l+32 hold same columns)
  a0 += __shfl_xor(a0, 32);
  a1 += __shfl_xor(a1, 32);
  a2 += __shfl_xor(a2, 32);
  a3 += __shfl_xor(a3, 32);
  if (half == 0) {
    float dn = dinv[node];
    float4 b = ((const float4*)bias)[col];
    uint2 o;
    o.x = bfpack(b.x + dn * a0, b.y + dn * a1);
    o.y = bfpack(b.z + dn * a2, b.w + dn * a3);
    ((uint2*)h)[(size_t)node * 32 + col] = o;
  }
}

// ---------------- CSR gather + fused head (layer 2): out = h2 @ Wh + bh
__global__ __launch_bounds__(256)
void k_aggr_head(const int* __restrict__ off, const int* __restrict__ csr,
                 const ushort* __restrict__ t, const float* __restrict__ dinv,
                 const float* __restrict__ bias, const float* __restrict__ Wh,
                 const float* __restrict__ bh, float* __restrict__ out) {
  int node = blockIdx.x * 4 + (threadIdx.x >> 6);
  if (node >= N_NODES) return;
  const int lane = threadIdx.x & 63;
  const int half = lane >> 5;
  const int col = lane & 31;
  const uint2* t2 = (const uint2*)t;
  int start = (node == 0) ? 0 : off[node - 1];
  int end = off[node];
  float a0 = 0.f, a1 = 0.f, a2 = 0.f, a3 = 0.f;
  if (half == 0) {
    uint2 u = t2[(size_t)node * 32 + col];
    a0 = bflo(u.x); a1 = bfhi(u.x); a2 = bflo(u.y); a3 = bfhi(u.y);
  }
  int e = start + half;
  for (; e + 6 < end; e += 8) {
    int s0 = csr[e], s1 = csr[e + 2], s2 = csr[e + 4], s3 = csr[e + 6];
    uint2 u0 = t2[(size_t)s0 * 32 + col];
    uint2 u1 = t2[(size_t)s1 * 32 + col];
    uint2 u2 = t2[(size_t)s2 * 32 + col];
    uint2 u3 = t2[(size_t)s3 * 32 + col];
    a0 += (bflo(u0.x) + bflo(u1.x)) + (bflo(u2.x) + bflo(u3.x));
    a1 += (bfhi(u0.x) + bfhi(u1.x)) + (bfhi(u2.x) + bfhi(u3.x));
    a2 += (bflo(u0.y) + bflo(u1.y)) + (bflo(u2.y) + bflo(u3.y));
    a3 += (bfhi(u0.y) + bfhi(u1.y)) + (bfhi(u2.y) + bfhi(u3.y));
  }
  for (; e < end; e += 2) {
    uint2 u = t2[(size_t)csr[e] * 32 + col];
    a0 += bflo(u.x); a1 += bfhi(u.x); a2 += bflo(u.y); a3 += bfhi(u.y);
  }
  a0 += __shfl_xor(a0, 32);
  a1 += __shfl_xor(a1, 32);
  a2 += __shfl_xor(a2, 32);
  a3 += __shfl_xor(a3, 32);
  // h2 cols 4c..4c+3 in fp32 (no bf16 round)
  float dn = dinv[node];
  float4 b = ((const float4*)bias)[col];
  float h0 = b.x + dn * a0, h1 = b.y + dn * a1;
  float h2 = b.z + dn * a2, h3 = b.w + dn * a3;
  // head: Wh[128][2] row-major -> float4 pairs
  float4 w01 = ((const float4*)Wh)[2 * col];      // Wh[4c],[4c+1]
  float4 w23 = ((const float4*)Wh)[2 * col + 1];  // Wh[4c+2],[4c+3]
  float s0 = h0 * w01.x + h1 * w01.z + h2 * w23.x + h3 * w23.z;
  float s1 = h0 * w01.y + h1 * w01.w + h2 * w23.y + h3 * w23.w;
#pragma unroll
  for (int o = 16; o > 0; o >>= 1) {  // halves already merged; reduce 32
    s0 += __shfl_xor(s0, o);
    s1 += __shfl_xor(s1, o);
  }
  if (lane == 0) {
    reinterpret_cast<float2*>(out)[node] = make_float2(s0 + bh[0], s1 + bh[1]);
  }
}

// --------------------------------------------- fp32 fallback (small ws) ----
__global__ __launch_bounds__(256) void k_count(const int* __restrict__ eidx,
                                               const int* __restrict__ flag,
                                               int* __restrict__ off) {
  int e = blockIdx.x * 256 + threadIdx.x;
  int is64 = *flag;
  if (e < N_EDGES) {
    unsigned d = (unsigned)get_dst(eidx, is64, e);
    if (d < N_NODES) atomicAdd(&off[d], 1);
  }
}

__global__ __launch_bounds__(256) void k_dinv_old(const int* __restrict__ off,
                                                  float* __restrict__ dinv) {
  int i = blockIdx.x * 256 + threadIdx.x;
  if (i < N_NODES) dinv[i] = rsqrtf(1.0f + (float)off[i]);
}

template <int K>
__global__ __launch_bounds__(256)
void k_gemm(const float* __restrict__ A, const float* __restrict__ B,
            const float* __restrict__ bias, const float* __restrict__ scale,
            float* __restrict__ C, const int do_relu) {
  __shared__ float As[64][33];
  const int tid = threadIdx.x;
  const int tx = tid & 15;
  const int ty = tid >> 4;
  const int m0 = blockIdx.x * 64;

  float acc[4][8];
#pragma unroll
  for (int i = 0; i < 4; ++i)
#pragma unroll
    for (int j = 0; j < 8; ++j) acc[i][j] = 0.f;

  const int rs = tid >> 2;
  const int ks = (tid & 3) * 8;

  for (int k0 = 0; k0 < K; k0 += 32) {
    float av8[8];
    const int gm = m0 + rs;
    if (gm < N_NODES) {
      load8(&A[(size_t)gm * K + k0 + ks], av8);
    } else {
#pragma unroll
      for (int j = 0; j < 8; ++j) av8[j] = 0.f;
    }
    __syncthreads();
#pragma unroll
    for (int j = 0; j < 8; ++j) As[rs][ks + j] = av8[j];
    __syncthreads();

    const float* Bp = B + (size_t)k0 * DIM_H + tx * 8;
#pragma unroll 4
    for (int k = 0; k < 32; ++k) {
      float bv[8];
      load8(Bp + (size_t)k * DIM_H, bv);
      float av[4];
#pragma unroll
      for (int rr = 0; rr < 4; ++rr) av[rr] = As[ty * 4 + rr][k];
#pragma unroll
      for (int rr = 0; rr < 4; ++rr)
#pragma unroll
        for (int cc = 0; cc < 8; ++cc)
          acc[rr][cc] = fmaf(av[rr], bv[cc], acc[rr][cc]);
    }
  }

  float bs[8];
  if (bias) {
    load8(bias + tx * 8, bs);
  } else {
#pragma unroll
    for (int j = 0; j < 8; ++j) bs[j] = 0.f;
  }
#pragma unroll
  for (int rr = 0; rr < 4; ++rr) {
    const int gm = m0 + ty * 4 + rr;
    if (gm < N_NODES) {
      float sc = scale ? scale[gm] : 1.0f;
      float v[8];
#pragma unroll
      for (int cc = 0; cc < 8; ++cc) {
        float t = acc[rr][cc] + bs[cc];
        if (do_relu) t = fmaxf(t, 0.f);
        v[cc] = t * sc;
      }
      float* Cp = &C[(size_t)gm * DIM_H + tx * 8];
      reinterpret_cast<float4*>(Cp)[0] = make_float4(v[0], v[1], v[2], v[3]);
      reinterpret_cast<float4*>(Cp)[1] = make_float4(v[4], v[5], v[6], v[7]);
    }
  }
}

__global__ __launch_bounds__(256)
void k_aggr_init(const float* __restrict__ t, const float* __restrict__ dinv,
                 const float* __restrict__ bias, float* __restrict__ h) {
  int idx = blockIdx.x * 256 + threadIdx.x;
  if (idx < N_NODES * DIM_H) {
    int i = idx >> 7;
    int c = idx & 127;
    float d = dinv[i];
    h[idx] = bias[c] + t[idx] * d * d;
  }
}

__global__ __launch_bounds__(256)
void k_aggr_edges(const int* __restrict__ eidx, const int* __restrict__ flag,
                  const float* __restrict__ t, const float* __restrict__ dinv,
                  float* __restrict__ h) {
  int e = blockIdx.x * 2 + (threadIdx.x >> 7);
  int c = threadIdx.x & 127;
  int is64 = *flag;
  if (e < N_EDGES) {
    unsigned s = (unsigned)get_src(eidx, is64, e);
    unsigned d = (unsigned)get_dst(eidx, is64, e);
    if (s < N_NODES && d < N_NODES) {
      float nrm = dinv[s] * dinv[d];
      unsafeAtomicAdd(&h[(size_t)d * DIM_H + c], t[(size_t)s * DIM_H + c] * nrm);
    }
  }
}

__global__ __launch_bounds__(256)
void k_head_f32(const float* __restrict__ h, const float* __restrict__ Wh,
                const float* __restrict__ bh, float* __restrict__ out) {
  int node = blockIdx.x * 4 + (threadIdx.x >> 6);
  int lane = threadIdx.x & 63;
  if (node >= N_NODES) return;
  float h0 = h[(size_t)node * DIM_H + lane];
  float h1 = h[(size_t)node * DIM_H + 64 + lane];
  float s0 = h0 * Wh[lane * 2 + 0] + h1 * Wh[(lane + 64) * 2 + 0];
  float s1 = h0 * Wh[lane * 2 + 1] + h1 * Wh[(lane + 64) * 2 + 1];
#pragma unroll
  for (int off = 32; off > 0; off >>= 1) {
    s0 += __shfl_down(s0, off);
    s1 += __shfl_down(s1, off);
  }
  if (lane == 0) {
    reinterpret_cast<float2*>(out)[node] = make_float2(s0 + bh[0], s1 + bh[1]);
  }
}

// ---------------------------------------------------------------- launch
extern "C" void kernel_launch(void* const* d_in, const int* in_sizes, int n_in,
                              void* d_out, int out_size, void* d_ws, size_t ws_size,
                              hipStream_t stream) {
  (void)in_sizes; (void)n_in; (void)out_size;
  const int* eidx = (const int*)d_in[0];
  const float* x  = (const float*)d_in[1];
  const float* Wi = (const float*)d_in[2];
  const float* bi = (const float*)d_in[3];
  const float* W1 = (const float*)d_in[4];
  const float* b1 = (const float*)d_in[5];
  const float* W2 = (const float*)d_in[6];
  const float* b2 = (const float*)d_in[7];
  const float* Wh = (const float*)d_in[8];
  const float* bh = (const float*)d_in[9];
  float* out = (float*)d_out;

  const int gE  = (N_EDGES + 255) / 256;
  const int gM  = (N_NODES + 63) / 64;
  const int gW  = (N_NODES + 3) / 4;

  char* ws = (char*)d_ws;
  int* flag = (int*)ws;
  k_detect<<<1, 1024, 0, stream>>>(eidx, flag);

  const size_t need1 = 65128448;

  if (ws_size >= need1) {
    int*      bcnt  = (int*)(ws + 4096);
    int*      bbase = (int*)(ws + 57344);
    ushort*   bfWi  = (ushort*)(ws + 65536);
    ushort*   bfW1  = (ushort*)(ws + 196608);
    ushort*   bfW2  = (ushort*)(ws + 262144);
    int*      off   = (int*)(ws + 327680);
    float*    dinv  = (float*)(ws + 728064);
    int*      csr   = (int*)(ws + 1128448);
    unsigned* ebuf  = (unsigned*)(ws + 7528448);
    ushort*   bufA  = (ushort*)(ws + 13928448);
    ushort*   bufB  = (ushort*)(ws + 39528448);

    // bucketed CSR build (LDS-aggregated, padded counters)
    k_zero<<<(NBKT * CPAD + 255) / 256, 256, 0, stream>>>(bcnt, NBKT * CPAD);
    k_binc<<<NBLK, 1024, 0, stream>>>(eidx, flag, bcnt);
    k_bscan<<<1, 1024, 0, stream>>>(bcnt, bbase);
    k_bin<<<NBLK, 1024, 0, stream>>>(eidx, flag, bcnt, ebuf);
    k_csr<<<NBKT, 256, 0, stream>>>(bbase, ebuf, off, dinv, csr);

    // weight fragment split
    k_bsplit<<<16, 256, 0, stream>>>(Wi, 8, bfWi);
    k_bsplit<<<8, 256, 0, stream>>>(W1, 4, bfW1);
    k_bsplit<<<8, 256, 0, stream>>>(W2, 4, bfW2);

    // h1 = relu(x @ Wi + bi)           [bf16]
    k_gemm_x<DIM_IN><<<gM, 256, 0, stream>>>(x, bfWi, bi, bufA);
    // layer 1: t = (h1 @ W1) * dinv ; h2 = b1 + dinv*(self + gather)
    k_gemm_h<<<gM, 256, 0, stream>>>(bufA, bfW1, dinv, bufB);
    k_aggr_csr<<<gW, 256, 0, stream>>>(off, csr, bufB, dinv, b1, bufA);
    // layer 2 + fused head
    k_gemm_h<<<gM, 256, 0, stream>>>(bufA, bfW2, dinv, bufB);
    k_aggr_head<<<gW, 256, 0, stream>>>(off, csr, bufB, dinv, b2, Wh, bh, out);
  } else {
    // fallback: fp32 atomic-scatter path (~103 MB)
    const int gN  = (N_NODES + 255) / 256;
    int*   off  = (int*)(ws + 4096);
    float* dinv = (float*)(ws + 404480);
    float* fbA  = (float*)(ws + 804864);
    float* fbB  = (float*)(ws + 804864 + (size_t)N_NODES * DIM_H * 4);
    const int gNH = (N_NODES * DIM_H + 255) / 256;
    const int gE2 = (N_EDGES + 1) / 2;
    k_zero<<<gN, 256, 0, stream>>>(off, N_NODES);
    k_count<<<gE, 256, 0, stream>>>(eidx, flag, off);
    k_dinv_old<<<gN, 256, 0, stream>>>(off, dinv);

    k_gemm<DIM_IN><<<gM, 256, 0, stream>>>(x, Wi, bi, nullptr, fbA, 1);
    k_gemm<DIM_H><<<gM, 256, 0, stream>>>(fbA, W1, nullptr, nullptr, fbB, 0);
    k_aggr_init<<<gNH, 256, 0, stream>>>(fbB, dinv, b1, fbA);
    k_aggr_edges<<<gE2, 256, 0, stream>>>(eidx, flag, fbB, dinv, fbA);
    k_gemm<DIM_H><<<gM, 256, 0, stream>>>(fbA, W2, nullptr, nullptr, fbB, 0);
    k_aggr_init<<<gNH, 256, 0, stream>>>(fbB, dinv, b2, fbA);
    k_aggr_edges<<<gE2, 256, 0, stream>>>(eidx, flag, fbB, dinv, fbA);
    k_head_f32<<<gW, 256, 0, stream>>>(fbA, Wh, bh, out);
  }
}